// Round 6
// baseline (4446.999 us; speedup 1.0000x reference)
//
#include <hip/hip_runtime.h>
#include <hip/hip_bf16.h>
#include <float.h>
#include <math.h>

#define BSZ    32
#define SRCLEN 128
#define DM     512
#define VOCAB  50257
#define VB     393            // vocab blocks of 128 (393*128 = 50304)
#define TGT    48             // max_tgt_len
#define TOKC   50             // TGT+2
#define SCC    49             // TGT+1
#define PAD_ID 1
#define UNK_ID 3
#define EOS_ID 2
#define NEG    (-1e30f)

typedef __attribute__((ext_vector_type(8))) short bf16x8;
typedef __attribute__((ext_vector_type(4))) float f32x4;

// ---------------------------------------------------------------- helpers
__device__ inline unsigned pkbf(float lo, float hi) {
    unsigned a = __float_as_uint(lo), b = __float_as_uint(hi);
    a = (a + 0x7fffu + ((a >> 16) & 1u)) >> 16;
    b = (b + 0x7fffu + ((b >> 16) & 1u)) >> 16;
    return (a & 0xffffu) | (b << 16);
}

__device__ inline unsigned short f2bf(float x) {
    unsigned u = __float_as_uint(x);
    u = (u + 0x7fffu + ((u >> 16) & 1u)) >> 16;
    return (unsigned short)u;
}

__device__ inline void ce_pair(float& av, int& ai, float& bv, int& bi) {
    bool keep = (av > bv) || (av == bv && ai < bi);
    if (!keep) {
        float tv = av; av = bv; bv = tv;
        int ti = ai; ai = bi; bi = ti;
    }
}

// FULL 8-stage bitonic merge (R1 verbatim).
__device__ inline void merge4(float a0v[4], int a0i[4], float bv[4], int bi[4]) {
    float e[8]; int ix[8];
#pragma unroll
    for (int c = 0; c < 4; c++) { e[c] = a0v[c]; ix[c] = a0i[c]; e[4 + c] = bv[c]; ix[4 + c] = bi[c]; }
    ce_pair(e[0], ix[0], e[4], ix[4]); ce_pair(e[1], ix[1], e[5], ix[5]);
    ce_pair(e[2], ix[2], e[6], ix[6]); ce_pair(e[3], ix[3], e[7], ix[7]);
    ce_pair(e[2], ix[2], e[4], ix[4]); ce_pair(e[3], ix[3], e[5], ix[5]);
    ce_pair(e[1], ix[1], e[2], ix[2]); ce_pair(e[3], ix[3], e[4], ix[4]);
#pragma unroll
    for (int c = 0; c < 4; c++) { a0v[c] = e[c]; a0i[c] = ix[c]; }
}

__device__ inline void osm_merge(float& m, float& s, float om, float os) {
    float nm = fmaxf(m, om);
    float sa = (m == -FLT_MAX) ? 0.f : s * expf(m - nm);
    float sb = (om == -FLT_MAX) ? 0.f : os * expf(om - nm);
    s = sa + sb; m = nm;
}

// async global->LDS, 16B per lane, dest = wave-uniform base + lane*16
__device__ inline void gll16(const void* g, void* l) {
    __builtin_amdgcn_global_load_lds(
        (const __attribute__((address_space(1))) void*)g,
        (__attribute__((address_space(3))) void*)l, 16, 0, 0);
}

// ----------------------------------------------------- embed fp32 -> bf16
__global__ void embed2bf_kernel(const float* __restrict__ e,
                                unsigned short* __restrict__ o) {
    size_t i = ((size_t)blockIdx.x * 256 + threadIdx.x) * 8;
    if (i >= (size_t)VOCAB * DM) return;
    float4 a = *(const float4*)(e + i);
    float4 b = *(const float4*)(e + i + 4);
    uint4 r = { pkbf(a.x, a.y), pkbf(a.z, a.w), pkbf(b.x, b.y), pkbf(b.z, b.w) };
    *(uint4*)(o + i) = r;
}

// ---------------------------------------------------------------- ctx partial
// R0 verbatim (proven 88us; R5's register-blocked variant spilled, 232us).
__global__ void ctx_partial_kernel(const int* __restrict__ src,
                                   const float* __restrict__ embed,
                                   const float* __restrict__ wenc,
                                   float* __restrict__ partial) {
    int b = blockIdx.x, jc = blockIdx.y, t = threadIdx.x;
    __shared__ float e[16][DM];
    for (int jj = 0; jj < 16; jj++) {
        int tok = src[b * SRCLEN + jc * 16 + jj];
        e[jj][t]       = embed[(size_t)tok * DM + t];
        e[jj][t + 256] = embed[(size_t)tok * DM + t + 256];
    }
    __syncthreads();
    float a0[16], a1[16];
#pragma unroll
    for (int jj = 0; jj < 16; jj++) { a0[jj] = 0.f; a1[jj] = 0.f; }
    for (int k = 0; k < DM; k += 4) {
        float w0[4], w1[4];
#pragma unroll
        for (int q = 0; q < 4; q++) {
            w0[q] = wenc[(k + q) * DM + t];
            w1[q] = wenc[(k + q) * DM + t + 256];
        }
#pragma unroll
        for (int jj = 0; jj < 16; jj++) {
            float4 ev = *(const float4*)&e[jj][k];
            a0[jj] += ev.x * w0[0]; a0[jj] += ev.y * w0[1];
            a0[jj] += ev.z * w0[2]; a0[jj] += ev.w * w0[3];
            a1[jj] += ev.x * w1[0]; a1[jj] += ev.y * w1[1];
            a1[jj] += ev.z * w1[2]; a1[jj] += ev.w * w1[3];
        }
    }
    float s0 = 0.f, s1 = 0.f;
#pragma unroll
    for (int jj = 0; jj < 16; jj++) { s0 += tanhf(a0[jj]); s1 += tanhf(a1[jj]); }
    partial[(size_t)(b * 8 + jc) * DM + t]       = s0;
    partial[(size_t)(b * 8 + jc) * DM + t + 256] = s1;
}

__global__ void ctx_reduce_kernel(const float* __restrict__ partial,
                                  float* __restrict__ ctx) {
    int b = blockIdx.x, t = threadIdx.x;
    float s = 0.f;
    for (int jc = 0; jc < 8; jc++) s += partial[(size_t)(b * 8 + jc) * DM + t];
    ctx[b * DM + t] = s * (1.0f / 128.0f);
}

// ---------------------------------------------------------------- hidden h
// R1 verbatim (128 blocks x 128 thr).
__global__ void hidden_kernel(const float* __restrict__ embed,
                              const float* __restrict__ wdec,
                              const float* __restrict__ bdec,
                              const float* __restrict__ ctx,
                              const int* __restrict__ prev_tok,
                              unsigned short* __restrict__ h,
                              int step0) {
    int t = threadIdx.x;                 // 0..127
    int r0 = blockIdx.x * 4;
    int d = blockIdx.y * 128 + t;
    __shared__ float e[4][DM];
    for (int i = 0; i < 4; i++) {
        int tok = step0 ? EOS_ID : prev_tok[r0 + i];
        for (int c = t; c < DM; c += 128)
            e[i][c] = embed[(size_t)tok * DM + c];
    }
    __syncthreads();
    float acc[4] = {0.f, 0.f, 0.f, 0.f};
#pragma unroll 2
    for (int k = 0; k < DM; k += 4) {
        float w[4];
#pragma unroll
        for (int q = 0; q < 4; q++) w[q] = wdec[(k + q) * DM + d];
#pragma unroll
        for (int i = 0; i < 4; i++) {
            float4 ev = *(const float4*)&e[i][k];
            acc[i] += ev.x * w[0]; acc[i] += ev.y * w[1];
            acc[i] += ev.z * w[2]; acc[i] += ev.w * w[3];
        }
    }
    float bb = bdec[d];
#pragma unroll
    for (int i = 0; i < 4; i++) {
        int r = r0 + i;
        int sent = step0 ? (r & 31) : (r >> 2);
        h[r * DM + d] = f2bf(tanhf(acc[i] + bb + ctx[sent * DM + d]));
    }
}

// ----------------------------------- MFMA logits GEMM + fused softmax/top4
// R6: staging rewritten to m97 pattern — global_load_lds width 16, LDS
// double-buffer (2 x (A 8KB + B 8KB) = 32KB), ONE barrier per K-step (its
// implicit vmcnt(0) drain completes the async stage). LDS layout identical
// to R1 (slot = kslice*128 + row, 16B each): wave w stages kslice w, inst q
// covers rows 64q+lane — lane-linear as the HW requires. Frag reads and all
// math are R1-verbatim. OOB vocab rows clamp to VOCAB-1 (finite garbage,
// never read: epilogue guards v < VOCAB).
__global__ void __launch_bounds__(256, 2)
gemm_topk(const unsigned short* __restrict__ hb,
          const unsigned short* __restrict__ ebf,
          float* __restrict__ pm, float* __restrict__ ps,
          float* __restrict__ pv, int* __restrict__ pi,
          int step0, int ensure) {
    __shared__ char smem[32768];
    short* As0 = (short*)smem;              // 8KB: [kslice][row][8 bf16]
    short* As1 = (short*)(smem + 8192);
    short* Bs0 = (short*)(smem + 16384);
    short* Bs1 = (short*)(smem + 24576);
    int t = threadIdx.x;
    int v0 = blockIdx.x * 128;
    int w = t >> 6, lane = t & 63;
    int quad = lane >> 4, lr = lane & 15;
    int vh = w & 1, hh = w >> 1;

    f32x4 acc[4][4];
#pragma unroll
    for (int i = 0; i < 4; i++)
#pragma unroll
        for (int j = 0; j < 4; j++) acc[i][j] = (f32x4){0.f, 0.f, 0.f, 0.f};

    // staging sources: inst q covers rows 64q+lane of the tile, kslice w
    int ar0 = v0 + lane;       if (ar0 > VOCAB - 1) ar0 = VOCAB - 1;
    int ar1 = v0 + 64 + lane;  if (ar1 > VOCAB - 1) ar1 = VOCAB - 1;
    const unsigned short* gA0 = ebf + (size_t)ar0 * DM + w * 8;
    const unsigned short* gA1 = ebf + (size_t)ar1 * DM + w * 8;
    const unsigned short* gB0 = hb + (size_t)lane * DM + w * 8;
    const unsigned short* gB1 = hb + (size_t)(64 + lane) * DM + w * 8;
    // LDS dest bases (wave-uniform): slot base = 128*w + 64*q, 8 shorts/slot
    const int sl0 = (128 * w) * 8, sl1 = (128 * w + 64) * 8;

    auto stage = [&](short* Ab, short* Bb, int kc) {
        gll16(gA0 + kc, Ab + sl0);
        gll16(gA1 + kc, Ab + sl1);
        gll16(gB0 + kc, Bb + sl0);
        gll16(gB1 + kc, Bb + sl1);
    };
    auto compute = [&](const short* Ab, const short* Bb) {
        bf16x8 af[4], bfr[4];
#pragma unroll
        for (int i = 0; i < 4; i++)
            af[i] = *(const bf16x8*)(Ab + quad * 1024 + (64 * vh + 16 * i + lr) * 8);
#pragma unroll
        for (int j = 0; j < 4; j++)
            bfr[j] = *(const bf16x8*)(Bb + quad * 1024 + (64 * hh + 16 * j + lr) * 8);
#pragma unroll
        for (int i = 0; i < 4; i++)
#pragma unroll
            for (int j = 0; j < 4; j++)
                acc[i][j] = __builtin_amdgcn_mfma_f32_16x16x32_bf16(
                    af[i], bfr[j], acc[i][j], 0, 0, 0);
    };

    stage(As0, Bs0, 0);
    __syncthreads();                        // drains vmcnt -> buf0 ready
#pragma unroll
    for (int kc = 0; kc < DM; kc += 64) {
        stage(As1, Bs1, kc + 32);           // kc+32 < DM always (kc <= 448)
        compute(As0, Bs0);
        __syncthreads();                    // buf1 staged; buf0 reads done
        if (kc + 64 < DM) stage(As0, Bs0, kc + 64);
        compute(As1, Bs1);
        __syncthreads();                    // buf0 staged; buf1 reads done
    }

    float* epim = (float*)smem;            // [128][2]
    float* epis = (float*)(smem + 1024);   // [128][2]
    float* epiv = (float*)(smem + 2048);   // [128][2][4]
    int*   epii = (int*)(smem + 6144);     // [128][2][4]

#pragma unroll
    for (int j = 0; j < 4; j++) {
        float m = -FLT_MAX, ssum = 0.f;
        float tv4[4] = {-FLT_MAX, -FLT_MAX, -FLT_MAX, -FLT_MAX};
        int ti4[4] = {0x7fffffff, 0x7fffffff, 0x7fffffff, 0x7fffffff};
#pragma unroll
        for (int i = 0; i < 4; i++)
#pragma unroll
            for (int reg = 0; reg < 4; reg++) {
                int v = v0 + 64 * vh + 16 * i + quad * 4 + reg;
                if (v < VOCAB) m = fmaxf(m, acc[i][j][reg]);
            }
#pragma unroll
        for (int i = 0; i < 4; i++)
#pragma unroll
            for (int reg = 0; reg < 4; reg++) {
                int v = v0 + 64 * vh + 16 * i + quad * 4 + reg;  // ascending
                if (v >= VOCAB) continue;
                float raw = acc[i][j][reg];
                ssum += __expf(raw - m);
                float mv = raw;
                if (v == PAD_ID) mv = NEG;
                if (step0 && v == EOS_ID) mv = NEG;
                if (ensure && v != EOS_ID) mv = NEG;
                if (mv > tv4[3]) {   // strict > keeps earliest (smallest v)
                    tv4[3] = mv; ti4[3] = v;
                    if (tv4[3] > tv4[2]) { float a = tv4[3]; tv4[3] = tv4[2]; tv4[2] = a; int b = ti4[3]; ti4[3] = ti4[2]; ti4[2] = b; }
                    if (tv4[2] > tv4[1]) { float a = tv4[2]; tv4[2] = tv4[1]; tv4[1] = a; int b = ti4[2]; ti4[2] = ti4[1]; ti4[1] = b; }
                    if (tv4[1] > tv4[0]) { float a = tv4[1]; tv4[1] = tv4[0]; tv4[0] = a; int b = ti4[1]; ti4[1] = ti4[0]; ti4[0] = b; }
                }
            }
#pragma unroll
        for (int mask = 16; mask <= 32; mask <<= 1) {
            float om = __shfl_xor(m, mask);
            float os = __shfl_xor(ssum, mask);
            float ov[4]; int oi[4];
#pragma unroll
            for (int c = 0; c < 4; c++) {
                ov[c] = __shfl_xor(tv4[c], mask);
                oi[c] = __shfl_xor(ti4[c], mask);
            }
            osm_merge(m, ssum, om, os);
            merge4(tv4, ti4, ov, oi);
        }
        if (quad == 0) {
            int hrow = 64 * hh + 16 * j + lr;
            int slot = hrow * 2 + vh;
            epim[slot] = m; epis[slot] = ssum;
#pragma unroll
            for (int c = 0; c < 4; c++) { epiv[slot * 4 + c] = tv4[c]; epii[slot * 4 + c] = ti4[c]; }
        }
    }
    __syncthreads();
    if (t < 128) {
        int s0 = t * 2, s1 = t * 2 + 1;
        float m = epim[s0], ssum = epis[s0];
        float tv4[4]; int ti4[4];
#pragma unroll
        for (int c = 0; c < 4; c++) { tv4[c] = epiv[s0 * 4 + c]; ti4[c] = epii[s0 * 4 + c]; }
        float ov[4]; int oi[4];
#pragma unroll
        for (int c = 0; c < 4; c++) { ov[c] = epiv[s1 * 4 + c]; oi[c] = epii[s1 * 4 + c]; }
        osm_merge(m, ssum, epim[s1], epis[s1]);
        merge4(tv4, ti4, ov, oi);
        int pidx = t * VB + blockIdx.x;
        pm[pidx] = m;
        ps[pidx] = ssum;
#pragma unroll
        for (int c = 0; c < 4; c++) { pv[pidx * 4 + c] = tv4[c]; pi[pidx * 4 + c] = ti4[c]; }
    }
}

// ------------------------------------------- fused row-reduce + beam update
// R1 verbatim.
__global__ void reduce_beam(int s,
                            const float* __restrict__ pm, const float* __restrict__ ps,
                            const float* __restrict__ pv, const int* __restrict__ pi,
                            const int* __restrict__ tok_cur, int* __restrict__ tok_nxt,
                            const float* __restrict__ sc_cur, float* __restrict__ sc_nxt,
                            int* __restrict__ prev_tok, float* __restrict__ prev_score,
                            float* __restrict__ bestfin) {
    int b = blockIdx.x, t = threadIdx.x;
    int g = t >> 6, lane = t & 63;
    int r = b * 4 + g;
    __shared__ float cs[16], sent[16];
    __shared__ int ct[16];
    __shared__ int parent[4], tsel[4];
    __shared__ float ssel[4];

    float m = -FLT_MAX, ssum = 0.f;
    float tv4[4] = {-FLT_MAX, -FLT_MAX, -FLT_MAX, -FLT_MAX};
    int ti4[4] = {0x7fffffff, 0x7fffffff, 0x7fffffff, 0x7fffffff};
    for (int j = lane; j < VB; j += 64) {
        int pidx = r * VB + j;
        float ov[4]; int oi[4];
#pragma unroll
        for (int c = 0; c < 4; c++) { ov[c] = pv[pidx * 4 + c]; oi[c] = pi[pidx * 4 + c]; }
        osm_merge(m, ssum, pm[pidx], ps[pidx]);
        merge4(tv4, ti4, ov, oi);
    }
#pragma unroll
    for (int mask = 1; mask <= 32; mask <<= 1) {
        float om = __shfl_xor(m, mask);
        float os = __shfl_xor(ssum, mask);
        float ov[4]; int oi[4];
#pragma unroll
        for (int c = 0; c < 4; c++) {
            ov[c] = __shfl_xor(tv4[c], mask);
            oi[c] = __shfl_xor(ti4[c], mask);
        }
        osm_merge(m, ssum, om, os);
        merge4(tv4, ti4, ov, oi);
    }
    if (lane == 0) {
        float lse_r = m + logf(ssum);
        float prev = prev_score[r];
        for (int c = 0; c < 4; c++) {
            float val = tv4[c];
            float lp = (val < -9.0e29f) ? NEG : (val - lse_r);
            float csv = lp + prev;
            if (csv < -9.0e29f) csv = NEG;
            cs[g * 4 + c] = csv;
            sent[g * 4 + c] = csv / (float)(s + 1);
            ct[g * 4 + c] = ti4[c];
        }
    }
    __syncthreads();
    if (t == 0) {
        int top[8], c2[8];
        float s2[8], cs2[8];
        unsigned used = 0;
        for (int o = 0; o < 8; o++) {
            float best = -FLT_MAX; int bi = 0;
            for (int i = 0; i < 16; i++)
                if (!((used >> i) & 1u) && sent[i] > best) { best = sent[i]; bi = i; }
            used |= 1u << bi;
            top[o] = bi; s2[o] = best; c2[o] = ct[bi]; cs2[o] = cs[bi];
        }
        float bf = bestfin[b];
        for (int c = 0; c < 4; c++)
            if (c2[c] == EOS_ID) bf = fmaxf(bf, s2[c]);
        bestfin[b] = bf;
        float sm[8];
        for (int c = 0; c < 8; c++) sm[c] = (c2[c] == EOS_ID) ? NEG : s2[c];
        unsigned used2 = 0;
        for (int o = 0; o < 4; o++) {
            float best = -FLT_MAX; int bi = 0;
            for (int i = 0; i < 8; i++)
                if (!((used2 >> i) & 1u) && sm[i] > best) { best = sm[i]; bi = i; }
            used2 |= 1u << bi;
            parent[o] = top[bi] >> 2;
            tsel[o] = c2[bi];
            float sv = cs2[bi];
            if (sv < -9.0e29f) sv = NEG;
            ssel[o] = sv;
        }
        for (int o = 0; o < 4; o++) {
            prev_tok[b * 4 + o] = tsel[o];
            prev_score[b * 4 + o] = ssel[o];
        }
    }
    __syncthreads();
    for (int idx = t; idx < 4 * TOKC; idx += 256) {
        int i = idx / TOKC, c = idx % TOKC;
        int src = b * 4 + parent[i], dst = b * 4 + i;
        tok_nxt[dst * TOKC + c] = (c == s + 1) ? tsel[i] : tok_cur[src * TOKC + c];
        if (c < SCC)
            sc_nxt[dst * SCC + c] = (c == s) ? ssel[i] : sc_cur[src * SCC + c];
    }
}

// ------------------------------------------- fused row-reduce + beam init
// R1 verbatim.
__global__ void reduce_init(const float* __restrict__ pm, const float* __restrict__ ps,
                            const float* __restrict__ pv, const int* __restrict__ pi,
                            int* __restrict__ tok0, float* __restrict__ sc0,
                            int* __restrict__ prev_tok, float* __restrict__ prev_score,
                            float* __restrict__ bestfin) {
    int b = blockIdx.x, lane = threadIdx.x;
    __shared__ int tk[4];
    __shared__ float s0sh[4];
    float m = -FLT_MAX, ssum = 0.f;
    float tv4[4] = {-FLT_MAX, -FLT_MAX, -FLT_MAX, -FLT_MAX};
    int ti4[4] = {0x7fffffff, 0x7fffffff, 0x7fffffff, 0x7fffffff};
    for (int j = lane; j < VB; j += 64) {
        int pidx = b * VB + j;
        float ov[4]; int oi[4];
#pragma unroll
        for (int c = 0; c < 4; c++) { ov[c] = pv[pidx * 4 + c]; oi[c] = pi[pidx * 4 + c]; }
        osm_merge(m, ssum, pm[pidx], ps[pidx]);
        merge4(tv4, ti4, ov, oi);
    }
#pragma unroll
    for (int mask = 1; mask <= 32; mask <<= 1) {
        float om = __shfl_xor(m, mask);
        float os = __shfl_xor(ssum, mask);
        float ov[4]; int oi[4];
#pragma unroll
        for (int c = 0; c < 4; c++) {
            ov[c] = __shfl_xor(tv4[c], mask);
            oi[c] = __shfl_xor(ti4[c], mask);
        }
        osm_merge(m, ssum, om, os);
        merge4(tv4, ti4, ov, oi);
    }
    if (lane == 0) {
        float lse_b = m + logf(ssum);
        for (int c = 0; c < 4; c++) {
            float val = tv4[c];
            float sc = (val < -9.0e29f) ? NEG : (val - lse_b);
            if (sc < -9.0e29f) sc = NEG;
            tk[c] = ti4[c]; s0sh[c] = sc;
            prev_tok[b * 4 + c] = ti4[c];
            prev_score[b * 4 + c] = sc;
        }
        bestfin[b] = NEG;
    }
    __syncthreads();
    for (int idx = lane; idx < 4 * TOKC; idx += 64) {
        int i = idx / TOKC, c = idx % TOKC;
        int dst = b * 4 + i;
        tok0[dst * TOKC + c] = (c == 0) ? EOS_ID : ((c == 1) ? tk[i] : PAD_ID);
        if (c < SCC) sc0[dst * SCC + c] = (c == 0) ? s0sh[i] : NEG;
    }
}

// ---------------------------------------------------------------- finalize
__global__ void finalize_kernel(const int* __restrict__ tok,
                                const float* __restrict__ sc,
                                const float* __restrict__ bf,
                                float* __restrict__ out) {
    int i = blockIdx.x * 256 + threadIdx.x;
    const int NTOK = 128 * TOKC;        // 6400
    const int NSC = 128 * SCC;          // 6272
    const int TOT = NTOK + NSC + 32;    // 12704
    if (i >= TOT) return;
    float v;
    if (i < NTOK) {
        int tv = tok[i];
        if (tv < 0) tv = 0;
        if (tv > VOCAB - 1) tv = VOCAB - 1;
        v = (float)tv;
    } else {
        v = (i < NTOK + NSC) ? sc[i - NTOK] : bf[i - NTOK - NSC];
        if (!(v <= 0.0f)) v = 0.0f;
        if (v < -9.0e29f) v = NEG;
    }
    out[i] = v;
}

// ---------------------------------------------------------------- launch
extern "C" void kernel_launch(void* const* d_in, const int* in_sizes, int n_in,
                              void* d_out, int out_size, void* d_ws, size_t ws_size,
                              hipStream_t stream) {
    const int* src = (const int*)d_in[0];
    const float* embed = (const float*)d_in[1];
    const float* wenc = (const float*)d_in[2];
    const float* wdec = (const float*)d_in[3];
    const float* bdec = (const float*)d_in[4];

    char* w = (char*)d_ws;
    size_t off = 0;
    auto alloc = [&](size_t bytes) -> char* {
        char* p = w + off;
        off += (bytes + 255) & ~(size_t)255;
        return p;
    };
    int*   ptok   = (int*)alloc(128 * 4);
    float* pscore = (float*)alloc(128 * 4);
    float* bfin   = (float*)alloc(BSZ * 4);
    int*   tokb0  = (int*)alloc(128 * TOKC * 4);
    int*   tokb1  = (int*)alloc(128 * TOKC * 4);
    float* scb0   = (float*)alloc(128 * SCC * 4);
    float* scb1   = (float*)alloc(128 * SCC * 4);
    unsigned short* h = (unsigned short*)alloc((size_t)128 * DM * 2);
    float* ctx    = (float*)alloc((size_t)BSZ * DM * 4);
    float* encpart= (float*)alloc((size_t)BSZ * 8 * DM * 4);
    const size_t NP = (size_t)128 * VB;
    float* pm = (float*)alloc(NP * 4);
    float* ps = (float*)alloc(NP * 4);
    float* pv = (float*)alloc(NP * 4 * 4);
    int*   pi = (int*)alloc(NP * 4 * 4);
    unsigned short* ebf = (unsigned short*)alloc((size_t)VOCAB * DM * 2);
    int* tokb[2] = {tokb0, tokb1};
    float* scb[2] = {scb0, scb1};

    // one-time embed -> bf16 (RNE identical to old in-gemm pkbf)
    embed2bf_kernel<<<(VOCAB * DM / 8 + 255) / 256, 256, 0, stream>>>(embed, ebf);

    // encoder context (R0 proven)
    ctx_partial_kernel<<<dim3(BSZ, 8), 256, 0, stream>>>(src, embed, wenc, encpart);
    ctx_reduce_kernel<<<BSZ, 512, 0, stream>>>(encpart, ctx);

    // step 0 (all 128 h rows defined; rows 32..127 mirror sentences)
    hidden_kernel<<<dim3(32, 4), 128, 0, stream>>>(embed, wdec, bdec, ctx, ptok, h, 1);
    gemm_topk<<<VB, 256, 0, stream>>>(h, ebf, pm, ps, pv, pi, 1, 0);
    reduce_init<<<BSZ, 64, 0, stream>>>(pm, ps, pv, pi, tokb[0], scb[0],
                                        ptok, pscore, bfin);

    // steps 1..48
    for (int s = 1; s <= TGT; s++) {
        hidden_kernel<<<dim3(32, 4), 128, 0, stream>>>(embed, wdec, bdec, ctx, ptok, h, 0);
        gemm_topk<<<VB, 256, 0, stream>>>(h, ebf, pm, ps, pv, pi, 0, (s == TGT) ? 1 : 0);
        int cur = (s - 1) & 1, nxt = s & 1;
        reduce_beam<<<BSZ, 256, 0, stream>>>(s, pm, ps, pv, pi,
                                             tokb[cur], tokb[nxt], scb[cur], scb[nxt],
                                             ptok, pscore, bfin);
    }

    // final parity: step 48 wrote buffer 0
    finalize_kernel<<<50, 256, 0, stream>>>(tokb[0], scb[0], bfin,
                                            (float*)d_out);
}

// Round 7
// 4093.134 us; speedup vs baseline: 1.0865x; 1.0865x over previous
//
#include <hip/hip_runtime.h>
#include <hip/hip_bf16.h>
#include <float.h>
#include <math.h>

#define BSZ    32
#define SRCLEN 128
#define DM     512
#define VOCAB  50257
#define VB     393            // vocab blocks of 128 (393*128 = 50304)
#define TGT    48             // max_tgt_len
#define TOKC   50             // TGT+2
#define SCC    49             // TGT+1
#define PAD_ID 1
#define UNK_ID 3
#define EOS_ID 2
#define NEG    (-1e30f)

typedef __attribute__((ext_vector_type(8))) short bf16x8;
typedef __attribute__((ext_vector_type(4))) float f32x4;

// ---------------------------------------------------------------- helpers
__device__ inline unsigned pkbf(float lo, float hi) {
    unsigned a = __float_as_uint(lo), b = __float_as_uint(hi);
    a = (a + 0x7fffu + ((a >> 16) & 1u)) >> 16;
    b = (b + 0x7fffu + ((b >> 16) & 1u)) >> 16;
    return (a & 0xffffu) | (b << 16);
}

__device__ inline unsigned short f2bf(float x) {
    unsigned u = __float_as_uint(x);
    u = (u + 0x7fffu + ((u >> 16) & 1u)) >> 16;
    return (unsigned short)u;
}

__device__ inline void ce_pair(float& av, int& ai, float& bv, int& bi) {
    bool keep = (av > bv) || (av == bv && ai < bi);
    if (!keep) {
        float tv = av; av = bv; bv = tv;
        int ti = ai; ai = bi; bi = ti;
    }
}

// FULL 8-stage bitonic merge (R1 verbatim).
__device__ inline void merge4(float a0v[4], int a0i[4], float bv[4], int bi[4]) {
    float e[8]; int ix[8];
#pragma unroll
    for (int c = 0; c < 4; c++) { e[c] = a0v[c]; ix[c] = a0i[c]; e[4 + c] = bv[c]; ix[4 + c] = bi[c]; }
    ce_pair(e[0], ix[0], e[4], ix[4]); ce_pair(e[1], ix[1], e[5], ix[5]);
    ce_pair(e[2], ix[2], e[6], ix[6]); ce_pair(e[3], ix[3], e[7], ix[7]);
    ce_pair(e[2], ix[2], e[4], ix[4]); ce_pair(e[3], ix[3], e[5], ix[5]);
    ce_pair(e[1], ix[1], e[2], ix[2]); ce_pair(e[3], ix[3], e[4], ix[4]);
#pragma unroll
    for (int c = 0; c < 4; c++) { a0v[c] = e[c]; a0i[c] = ix[c]; }
}

__device__ inline void osm_merge(float& m, float& s, float om, float os) {
    float nm = fmaxf(m, om);
    float sa = (m == -FLT_MAX) ? 0.f : s * expf(m - nm);
    float sb = (om == -FLT_MAX) ? 0.f : os * expf(om - nm);
    s = sa + sb; m = nm;
}

// ----------------------------------------------------- embed fp32 -> bf16
__global__ void embed2bf_kernel(const float* __restrict__ e,
                                unsigned short* __restrict__ o) {
    size_t i = ((size_t)blockIdx.x * 256 + threadIdx.x) * 8;
    if (i >= (size_t)VOCAB * DM) return;
    float4 a = *(const float4*)(e + i);
    float4 b = *(const float4*)(e + i + 4);
    uint4 r = { pkbf(a.x, a.y), pkbf(a.z, a.w), pkbf(b.x, b.y), pkbf(b.z, b.w) };
    *(uint4*)(o + i) = r;
}

// ---------------------------------------------------------------- ctx partial
// R7: 512 threads, 1 col/thread, acc[16]. Statement-for-statement the same
// math as R0 (same per-(token,col) k order, same tanh-sum order) but with
// 8 waves/block -> 2 waves/SIMD (R0 had 1) to hide the wenc L2 latency that
// held VALUBusy at 32%.
__global__ void __launch_bounds__(512)
ctx_partial_kernel(const int* __restrict__ src,
                   const float* __restrict__ embed,
                   const float* __restrict__ wenc,
                   float* __restrict__ partial) {
    int b = blockIdx.x, jc = blockIdx.y, t = threadIdx.x;   // t < 512
    __shared__ float e[16][DM];                             // 32 KB
    for (int jj = 0; jj < 16; jj++) {
        int tok = src[b * SRCLEN + jc * 16 + jj];
        e[jj][t] = embed[(size_t)tok * DM + t];
    }
    __syncthreads();
    float a0[16];
#pragma unroll
    for (int jj = 0; jj < 16; jj++) a0[jj] = 0.f;
    for (int k = 0; k < DM; k += 4) {
        float w0[4];
#pragma unroll
        for (int q = 0; q < 4; q++) w0[q] = wenc[(k + q) * DM + t];
#pragma unroll
        for (int jj = 0; jj < 16; jj++) {
            float4 ev = *(const float4*)&e[jj][k];
            a0[jj] += ev.x * w0[0]; a0[jj] += ev.y * w0[1];
            a0[jj] += ev.z * w0[2]; a0[jj] += ev.w * w0[3];
        }
    }
    float s0 = 0.f;
#pragma unroll
    for (int jj = 0; jj < 16; jj++) s0 += tanhf(a0[jj]);
    partial[(size_t)(b * 8 + jc) * DM + t] = s0;
}

__global__ void ctx_reduce_kernel(const float* __restrict__ partial,
                                  float* __restrict__ ctx) {
    int b = blockIdx.x, t = threadIdx.x;
    float s = 0.f;
    for (int jc = 0; jc < 8; jc++) s += partial[(size_t)(b * 8 + jc) * DM + t];
    ctx[b * DM + t] = s * (1.0f / 128.0f);
}

// ---------------------------------------------------------------- hidden h0
// Prologue only (step 0, all rows EOS); R1 verbatim.
__global__ void hidden_kernel(const float* __restrict__ embed,
                              const float* __restrict__ wdec,
                              const float* __restrict__ bdec,
                              const float* __restrict__ ctx,
                              unsigned short* __restrict__ h) {
    int t = threadIdx.x;                 // 0..127
    int r0 = blockIdx.x * 4;
    int d = blockIdx.y * 128 + t;
    __shared__ float e[4][DM];
    for (int i = 0; i < 4; i++) {
        for (int c = t; c < DM; c += 128)
            e[i][c] = embed[(size_t)EOS_ID * DM + c];
    }
    __syncthreads();
    float acc[4] = {0.f, 0.f, 0.f, 0.f};
#pragma unroll 2
    for (int k = 0; k < DM; k += 4) {
        float w[4];
#pragma unroll
        for (int q = 0; q < 4; q++) w[q] = wdec[(k + q) * DM + d];
#pragma unroll
        for (int i = 0; i < 4; i++) {
            float4 ev = *(const float4*)&e[i][k];
            acc[i] += ev.x * w[0]; acc[i] += ev.y * w[1];
            acc[i] += ev.z * w[2]; acc[i] += ev.w * w[3];
        }
    }
    float bb = bdec[d];
#pragma unroll
    for (int i = 0; i < 4; i++) {
        int r = r0 + i;
        int sent = (r & 31);
        h[r * DM + d] = f2bf(tanhf(acc[i] + bb + ctx[sent * DM + d]));
    }
}

// ----------------------------------- MFMA logits GEMM + fused softmax/top4
// R1 verbatim (register depth-2 prefetch — measured faster than R6's
// global_load_lds dbuf: 83.0 vs 88.3 us/step).
__global__ void __launch_bounds__(256, 2)
gemm_topk(const unsigned short* __restrict__ hb,
          const unsigned short* __restrict__ ebf,
          float* __restrict__ pm, float* __restrict__ ps,
          float* __restrict__ pv, int* __restrict__ pi,
          int step0, int ensure) {
    __shared__ char smem[16384];
    short* As = (short*)smem;
    short* Bs = (short*)(smem + 8192);
    int t = threadIdx.x;
    int v0 = blockIdx.x * 128;
    int w = t >> 6, lane = t & 63;
    int quad = lane >> 4, lr = lane & 15;
    int vh = w & 1, hh = w >> 1;
    int row2 = t >> 1, khalf = t & 1;

    f32x4 acc[4][4];
#pragma unroll
    for (int i = 0; i < 4; i++)
#pragma unroll
        for (int j = 0; j < 4; j++) acc[i][j] = (f32x4){0.f, 0.f, 0.f, 0.f};

    int arow = v0 + row2;
    bool aval = arow < VOCAB;
    const unsigned short* ga = ebf + (size_t)(aval ? arow : 0) * DM + khalf * 16;
    const unsigned short* gb = hb + row2 * DM + khalf * 16;

    uint4 a0_0 = *(const uint4*)(ga);
    uint4 a1_0 = *(const uint4*)(ga + 8);
    uint4 b0_0 = *(const uint4*)(gb);
    uint4 b1_0 = *(const uint4*)(gb + 8);
    uint4 a0_1 = *(const uint4*)(ga + 32);
    uint4 a1_1 = *(const uint4*)(ga + 40);
    uint4 b0_1 = *(const uint4*)(gb + 32);
    uint4 b1_1 = *(const uint4*)(gb + 40);

    auto kstep = [&](uint4& A0, uint4& A1, uint4& B0, uint4& B1, int kc) {
        if (!aval) {
            A0 = make_uint4(0u, 0u, 0u, 0u);
            A1 = make_uint4(0u, 0u, 0u, 0u);
        }
        __syncthreads();
        *(uint4*)(As + (khalf * 2) * 1024 + row2 * 8)     = A0;
        *(uint4*)(As + (khalf * 2 + 1) * 1024 + row2 * 8) = A1;
        *(uint4*)(Bs + (khalf * 2) * 1024 + row2 * 8)     = B0;
        *(uint4*)(Bs + (khalf * 2 + 1) * 1024 + row2 * 8) = B1;
        __syncthreads();
        if (kc + 64 < DM) {
            A0 = *(const uint4*)(ga + kc + 64);
            A1 = *(const uint4*)(ga + kc + 72);
            B0 = *(const uint4*)(gb + kc + 64);
            B1 = *(const uint4*)(gb + kc + 72);
        }
        bf16x8 af[4], bfr[4];
#pragma unroll
        for (int i = 0; i < 4; i++)
            af[i] = *(bf16x8*)(As + quad * 1024 + (64 * vh + 16 * i + lr) * 8);
#pragma unroll
        for (int j = 0; j < 4; j++)
            bfr[j] = *(bf16x8*)(Bs + quad * 1024 + (64 * hh + 16 * j + lr) * 8);
#pragma unroll
        for (int i = 0; i < 4; i++)
#pragma unroll
            for (int j = 0; j < 4; j++)
                acc[i][j] = __builtin_amdgcn_mfma_f32_16x16x32_bf16(
                    af[i], bfr[j], acc[i][j], 0, 0, 0);
    };

#pragma unroll
    for (int kc = 0; kc < DM; kc += 64) {
        kstep(a0_0, a1_0, b0_0, b1_0, kc);
        kstep(a0_1, a1_1, b0_1, b1_1, kc + 32);
    }
    __syncthreads();

    float* epim = (float*)smem;            // [128][2]
    float* epis = (float*)(smem + 1024);   // [128][2]
    float* epiv = (float*)(smem + 2048);   // [128][2][4]
    int*   epii = (int*)(smem + 6144);     // [128][2][4]

#pragma unroll
    for (int j = 0; j < 4; j++) {
        float m = -FLT_MAX, ssum = 0.f;
        float tv4[4] = {-FLT_MAX, -FLT_MAX, -FLT_MAX, -FLT_MAX};
        int ti4[4] = {0x7fffffff, 0x7fffffff, 0x7fffffff, 0x7fffffff};
#pragma unroll
        for (int i = 0; i < 4; i++)
#pragma unroll
            for (int reg = 0; reg < 4; reg++) {
                int v = v0 + 64 * vh + 16 * i + quad * 4 + reg;
                if (v < VOCAB) m = fmaxf(m, acc[i][j][reg]);
            }
#pragma unroll
        for (int i = 0; i < 4; i++)
#pragma unroll
            for (int reg = 0; reg < 4; reg++) {
                int v = v0 + 64 * vh + 16 * i + quad * 4 + reg;  // ascending
                if (v >= VOCAB) continue;
                float raw = acc[i][j][reg];
                ssum += __expf(raw - m);
                float mv = raw;
                if (v == PAD_ID) mv = NEG;
                if (step0 && v == EOS_ID) mv = NEG;
                if (ensure && v != EOS_ID) mv = NEG;
                if (mv > tv4[3]) {   // strict > keeps earliest (smallest v)
                    tv4[3] = mv; ti4[3] = v;
                    if (tv4[3] > tv4[2]) { float a = tv4[3]; tv4[3] = tv4[2]; tv4[2] = a; int b = ti4[3]; ti4[3] = ti4[2]; ti4[2] = b; }
                    if (tv4[2] > tv4[1]) { float a = tv4[2]; tv4[2] = tv4[1]; tv4[1] = a; int b = ti4[2]; ti4[2] = ti4[1]; ti4[1] = b; }
                    if (tv4[1] > tv4[0]) { float a = tv4[1]; tv4[1] = tv4[0]; tv4[0] = a; int b = ti4[1]; ti4[1] = ti4[0]; ti4[0] = b; }
                }
            }
#pragma unroll
        for (int mask = 16; mask <= 32; mask <<= 1) {
            float om = __shfl_xor(m, mask);
            float os = __shfl_xor(ssum, mask);
            float ov[4]; int oi[4];
#pragma unroll
            for (int c = 0; c < 4; c++) {
                ov[c] = __shfl_xor(tv4[c], mask);
                oi[c] = __shfl_xor(ti4[c], mask);
            }
            osm_merge(m, ssum, om, os);
            merge4(tv4, ti4, ov, oi);
        }
        if (quad == 0) {
            int hrow = 64 * hh + 16 * j + lr;
            int slot = hrow * 2 + vh;
            epim[slot] = m; epis[slot] = ssum;
#pragma unroll
            for (int c = 0; c < 4; c++) { epiv[slot * 4 + c] = tv4[c]; epii[slot * 4 + c] = ti4[c]; }
        }
    }
    __syncthreads();
    if (t < 128) {
        int s0 = t * 2, s1 = t * 2 + 1;
        float m = epim[s0], ssum = epis[s0];
        float tv4[4]; int ti4[4];
#pragma unroll
        for (int c = 0; c < 4; c++) { tv4[c] = epiv[s0 * 4 + c]; ti4[c] = epii[s0 * 4 + c]; }
        float ov[4]; int oi[4];
#pragma unroll
        for (int c = 0; c < 4; c++) { ov[c] = epiv[s1 * 4 + c]; oi[c] = epii[s1 * 4 + c]; }
        osm_merge(m, ssum, epim[s1], epis[s1]);
        merge4(tv4, ti4, ov, oi);
        int pidx = t * VB + blockIdx.x;
        pm[pidx] = m;
        ps[pidx] = ssum;
#pragma unroll
        for (int c = 0; c < 4; c++) { pv[pidx * 4 + c] = tv4[c]; pi[pidx * 4 + c] = ti4[c]; }
    }
}

// ------------------------------------------- fused beam update + next hidden
// 128 blocks x 256 thr: block = (sentence rg = blk>>2, col-slice q = blk&3).
// Each of the 4 blocks per sentence REDUNDANTLY computes the deterministic
// beam update (identical values -> concurrent identical writes are benign),
// then computes its 128-col slice of the sentence's 4 h-rows for the next
// step. No cross-block handshake. Redundancy races on pscore/bestfin are
// removed by ping-pong buffering them (read cur, write nxt) like tok/sc.
// Beam math is R1-verbatim; hidden math is R1-verbatim (t<128 active).
__global__ void __launch_bounds__(256)
beamhid(int s,
        const float* __restrict__ pm, const float* __restrict__ ps,
        const float* __restrict__ pv, const int* __restrict__ pi,
        const int* __restrict__ tok_cur, int* __restrict__ tok_nxt,
        const float* __restrict__ sc_cur, float* __restrict__ sc_nxt,
        const float* __restrict__ psc_cur, float* __restrict__ psc_nxt,
        const float* __restrict__ bf_cur, float* __restrict__ bf_nxt,
        const float* __restrict__ embed,
        const float* __restrict__ wdec,
        const float* __restrict__ bdec,
        const float* __restrict__ ctxv,
        unsigned short* __restrict__ h) {
    int blk = blockIdx.x, t = threadIdx.x;
    int rg = blk >> 2, q = blk & 3;
    __shared__ float r_cs[16], r_sent[16], r_ssel[4];
    __shared__ int r_ct[16], r_parent[4], r_tsel[4];
    __shared__ float e[4][DM];

    if (s == 0) {
        // ---- R1 reduce_init (scan on wave 0), writes to nxt buffers ----
        if (t < 64) {
            int lane = t;
            float m = -FLT_MAX, ssum = 0.f;
            float tv4[4] = {-FLT_MAX, -FLT_MAX, -FLT_MAX, -FLT_MAX};
            int ti4[4] = {0x7fffffff, 0x7fffffff, 0x7fffffff, 0x7fffffff};
            for (int j = lane; j < VB; j += 64) {
                int pidx = rg * VB + j;
                float ov[4]; int oi[4];
#pragma unroll
                for (int c = 0; c < 4; c++) { ov[c] = pv[pidx * 4 + c]; oi[c] = pi[pidx * 4 + c]; }
                osm_merge(m, ssum, pm[pidx], ps[pidx]);
                merge4(tv4, ti4, ov, oi);
            }
#pragma unroll
            for (int mask = 1; mask <= 32; mask <<= 1) {
                float om = __shfl_xor(m, mask);
                float os = __shfl_xor(ssum, mask);
                float ov[4]; int oi[4];
#pragma unroll
                for (int c = 0; c < 4; c++) {
                    ov[c] = __shfl_xor(tv4[c], mask);
                    oi[c] = __shfl_xor(ti4[c], mask);
                }
                osm_merge(m, ssum, om, os);
                merge4(tv4, ti4, ov, oi);
            }
            if (lane == 0) {
                float lse_b = m + logf(ssum);
                for (int c = 0; c < 4; c++) {
                    float val = tv4[c];
                    float sc = (val < -9.0e29f) ? NEG : (val - lse_b);
                    if (sc < -9.0e29f) sc = NEG;
                    r_tsel[c] = ti4[c]; r_ssel[c] = sc;
                    psc_nxt[rg * 4 + c] = sc;
                }
                bf_nxt[rg] = NEG;
            }
        }
        __syncthreads();
        for (int idx = t; idx < 4 * TOKC; idx += 256) {
            int i = idx / TOKC, c = idx % TOKC;
            int dst = rg * 4 + i;
            tok_nxt[dst * TOKC + c] = (c == 0) ? EOS_ID : ((c == 1) ? r_tsel[i] : PAD_ID);
            if (c < SCC) sc_nxt[dst * SCC + c] = (c == 0) ? r_ssel[i] : NEG;
        }
    } else {
        // ---- R1 reduce_beam (cur->nxt buffering) ----
        int g = t >> 6, lane = t & 63;
        int r = rg * 4 + g;
        float m = -FLT_MAX, ssum = 0.f;
        float tv4[4] = {-FLT_MAX, -FLT_MAX, -FLT_MAX, -FLT_MAX};
        int ti4[4] = {0x7fffffff, 0x7fffffff, 0x7fffffff, 0x7fffffff};
        for (int j = lane; j < VB; j += 64) {
            int pidx = r * VB + j;
            float ov[4]; int oi[4];
#pragma unroll
            for (int c = 0; c < 4; c++) { ov[c] = pv[pidx * 4 + c]; oi[c] = pi[pidx * 4 + c]; }
            osm_merge(m, ssum, pm[pidx], ps[pidx]);
            merge4(tv4, ti4, ov, oi);
        }
#pragma unroll
        for (int mask = 1; mask <= 32; mask <<= 1) {
            float om = __shfl_xor(m, mask);
            float os = __shfl_xor(ssum, mask);
            float ov[4]; int oi[4];
#pragma unroll
            for (int c = 0; c < 4; c++) {
                ov[c] = __shfl_xor(tv4[c], mask);
                oi[c] = __shfl_xor(ti4[c], mask);
            }
            osm_merge(m, ssum, om, os);
            merge4(tv4, ti4, ov, oi);
        }
        if (lane == 0) {
            float lse_r = m + logf(ssum);
            float prev = psc_cur[r];
            for (int c = 0; c < 4; c++) {
                float val = tv4[c];
                float lp = (val < -9.0e29f) ? NEG : (val - lse_r);
                float csv = lp + prev;
                if (csv < -9.0e29f) csv = NEG;
                r_cs[g * 4 + c] = csv;
                r_sent[g * 4 + c] = csv / (float)(s + 1);
                r_ct[g * 4 + c] = ti4[c];
            }
        }
        __syncthreads();
        if (t == 0) {
            int top[8], c2[8];
            float s2[8], cs2[8];
            unsigned used = 0;
            for (int o = 0; o < 8; o++) {
                float best = -FLT_MAX; int bi = 0;
                for (int i = 0; i < 16; i++)
                    if (!((used >> i) & 1u) && r_sent[i] > best) { best = r_sent[i]; bi = i; }
                used |= 1u << bi;
                top[o] = bi; s2[o] = best; c2[o] = r_ct[bi]; cs2[o] = r_cs[bi];
            }
            float bf = bf_cur[rg];
            for (int c = 0; c < 4; c++)
                if (c2[c] == EOS_ID) bf = fmaxf(bf, s2[c]);
            bf_nxt[rg] = bf;
            float sm[8];
            for (int c = 0; c < 8; c++) sm[c] = (c2[c] == EOS_ID) ? NEG : s2[c];
            unsigned used2 = 0;
            for (int o = 0; o < 4; o++) {
                float best = -FLT_MAX; int bi = 0;
                for (int i = 0; i < 8; i++)
                    if (!((used2 >> i) & 1u) && sm[i] > best) { best = sm[i]; bi = i; }
                used2 |= 1u << bi;
                r_parent[o] = top[bi] >> 2;
                r_tsel[o] = c2[bi];
                float sv = cs2[bi];
                if (sv < -9.0e29f) sv = NEG;
                r_ssel[o] = sv;
            }
            for (int o = 0; o < 4; o++)
                psc_nxt[rg * 4 + o] = r_ssel[o];
        }
        __syncthreads();
        for (int idx = t; idx < 4 * TOKC; idx += 256) {
            int i = idx / TOKC, c = idx % TOKC;
            int srcr = rg * 4 + r_parent[i], dst = rg * 4 + i;
            tok_nxt[dst * TOKC + c] = (c == s + 1) ? r_tsel[i] : tok_cur[srcr * TOKC + c];
            if (c < SCC)
                sc_nxt[dst * SCC + c] = (c == s) ? r_ssel[i] : sc_cur[srcr * SCC + c];
        }
    }

    // ---- next-step h rows for sentence rg, col slice q ----
    if (s < TGT) {
        __syncthreads();
        for (int i = 0; i < 4; i++) {
            int tok = r_tsel[i];
            for (int c = t; c < DM; c += 256)
                e[i][c] = embed[(size_t)tok * DM + c];
        }
        __syncthreads();
        if (t < 128) {
            int d = q * 128 + t;
            float acc[4] = {0.f, 0.f, 0.f, 0.f};
#pragma unroll 2
            for (int k = 0; k < DM; k += 4) {
                float w[4];
#pragma unroll
                for (int qq = 0; qq < 4; qq++) w[qq] = wdec[(k + qq) * DM + d];
#pragma unroll
                for (int i = 0; i < 4; i++) {
                    float4 ev = *(const float4*)&e[i][k];
                    acc[i] += ev.x * w[0]; acc[i] += ev.y * w[1];
                    acc[i] += ev.z * w[2]; acc[i] += ev.w * w[3];
                }
            }
            float bb = bdec[d];
#pragma unroll
            for (int i = 0; i < 4; i++) {
                int r = rg * 4 + i;
                h[r * DM + d] = f2bf(tanhf(acc[i] + bb + ctxv[rg * DM + d]));
            }
        }
    }
}

// ---------------------------------------------------------------- finalize
__global__ void finalize_kernel(const int* __restrict__ tok,
                                const float* __restrict__ sc,
                                const float* __restrict__ bf,
                                float* __restrict__ out) {
    int i = blockIdx.x * 256 + threadIdx.x;
    const int NTOK = 128 * TOKC;        // 6400
    const int NSC = 128 * SCC;          // 6272
    const int TOT = NTOK + NSC + 32;    // 12704
    if (i >= TOT) return;
    float v;
    if (i < NTOK) {
        int tv = tok[i];
        if (tv < 0) tv = 0;
        if (tv > VOCAB - 1) tv = VOCAB - 1;
        v = (float)tv;
    } else {
        v = (i < NTOK + NSC) ? sc[i - NTOK] : bf[i - NTOK - NSC];
        if (!(v <= 0.0f)) v = 0.0f;
        if (v < -9.0e29f) v = NEG;
    }
    out[i] = v;
}

// ---------------------------------------------------------------- launch
extern "C" void kernel_launch(void* const* d_in, const int* in_sizes, int n_in,
                              void* d_out, int out_size, void* d_ws, size_t ws_size,
                              hipStream_t stream) {
    const int* src = (const int*)d_in[0];
    const float* embed = (const float*)d_in[1];
    const float* wenc = (const float*)d_in[2];
    const float* wdec = (const float*)d_in[3];
    const float* bdec = (const float*)d_in[4];

    char* w = (char*)d_ws;
    size_t off = 0;
    auto alloc = [&](size_t bytes) -> char* {
        char* p = w + off;
        off += (bytes + 255) & ~(size_t)255;
        return p;
    };
    float* psb0   = (float*)alloc(128 * 4);
    float* psb1   = (float*)alloc(128 * 4);
    float* bfb0   = (float*)alloc(BSZ * 4);
    float* bfb1   = (float*)alloc(BSZ * 4);
    int*   tokb0  = (int*)alloc(128 * TOKC * 4);
    int*   tokb1  = (int*)alloc(128 * TOKC * 4);
    float* scb0   = (float*)alloc(128 * SCC * 4);
    float* scb1   = (float*)alloc(128 * SCC * 4);
    unsigned short* h = (unsigned short*)alloc((size_t)128 * DM * 2);
    float* ctx    = (float*)alloc((size_t)BSZ * DM * 4);
    float* encpart= (float*)alloc((size_t)BSZ * 8 * DM * 4);
    const size_t NP = (size_t)128 * VB;
    float* pm = (float*)alloc(NP * 4);
    float* ps = (float*)alloc(NP * 4);
    float* pv = (float*)alloc(NP * 4 * 4);
    int*   pi = (int*)alloc(NP * 4 * 4);
    unsigned short* ebf = (unsigned short*)alloc((size_t)VOCAB * DM * 2);
    int* tokb[2] = {tokb0, tokb1};
    float* scb[2] = {scb0, scb1};
    float* psb[2] = {psb0, psb1};
    float* bfb[2] = {bfb0, bfb1};

    // one-time embed -> bf16 (RNE identical to old in-gemm pkbf)
    embed2bf_kernel<<<(VOCAB * DM / 8 + 255) / 256, 256, 0, stream>>>(embed, ebf);

    // encoder context (512-thread latency-hiding variant)
    ctx_partial_kernel<<<dim3(BSZ, 8), 512, 0, stream>>>(src, embed, wenc, encpart);
    ctx_reduce_kernel<<<BSZ, 512, 0, stream>>>(encpart, ctx);

    // step-0 hidden (all rows EOS)
    hidden_kernel<<<dim3(32, 4), 128, 0, stream>>>(embed, wdec, bdec, ctx, h);

    // steps 0..48: gemm+topk, then fused beam-update + next hidden
    for (int s = 0; s <= TGT; s++) {
        gemm_topk<<<VB, 256, 0, stream>>>(h, ebf, pm, ps, pv, pi,
                                          (s == 0) ? 1 : 0, (s == TGT) ? 1 : 0);
        int cur = (s == 0) ? 1 : ((s - 1) & 1);   // s=0: cur unread
        int nxt = s & 1;                           // s=0 -> 0 (matches R1)
        beamhid<<<128, 256, 0, stream>>>(s, pm, ps, pv, pi,
                                         tokb[cur], tokb[nxt], scb[cur], scb[nxt],
                                         psb[cur], psb[nxt], bfb[cur], bfb[nxt],
                                         embed, wdec, bdec, ctx, h);
    }

    // final parity: step 48 wrote buffer 0
    finalize_kernel<<<50, 256, 0, stream>>>(tokb[0], scb[0], bfb[0],
                                            (float*)d_out);
}